// Round 4
// baseline (22699.492 us; speedup 1.0000x reference)
//
#include <hip/hip_runtime.h>

// ---------------------------------------------------------------------------
// RevRNN persistent kernel, round 4.
// Worker structure identical to round 3 (4 batch-groups x 8 col-groups,
// register-resident W, tag-packed u64 partial sums = flag+mean in one load,
// uncentered f16 state via relaxed agent u64 atomics).
// NEW: 224 ballast blocks spin dense FP32 FMAs until a done flag is set.
// Purpose: hold DPM/SMU at boost clock. Theory: at 1% utilization the shader
// clock drops ~4x, inflating every LLC round-trip leg of the serial chain.
// ---------------------------------------------------------------------------

#define T_TOT 2056
#define S_SEQ 2048
#define NWORK 32

typedef _Float16 f16x8 __attribute__((ext_vector_type(8)));
typedef float f32x4 __attribute__((ext_vector_type(4)));

__launch_bounds__(256, 1)
__global__ void rnn_kernel(const float* __restrict__ xg,
                           const float* __restrict__ hs,
                           const float* __restrict__ W0,
                           const float* __restrict__ W1,
                           float* __restrict__ out,
                           unsigned long long* __restrict__ partH0,
                           unsigned long long* __restrict__ partH1,
                           unsigned* __restrict__ done,
                           float* __restrict__ scratch,
                           unsigned* __restrict__ state0,
                           unsigned* __restrict__ state1) {
  const int tid = (int)threadIdx.x;

  // ---------------- ballast blocks: keep the clock domain busy -------------
  if (blockIdx.x >= NWORK) {
    float a0 = 1.0f + tid, a1 = 2.0f + tid, a2 = 3.0f + tid, a3 = 4.0f + tid;
    for (;;) {
#pragma unroll
      for (int i = 0; i < 128; ++i) {
        a0 = __builtin_fmaf(a0, 0.5f, 0.25f);
        a1 = __builtin_fmaf(a1, 0.5f, 0.26f);
        a2 = __builtin_fmaf(a2, 0.5f, 0.27f);
        a3 = __builtin_fmaf(a3, 0.5f, 0.28f);
      }
      if (__hip_atomic_load(done, __ATOMIC_RELAXED, __HIP_MEMORY_SCOPE_AGENT))
        break;
    }
    scratch[tid] = a0 + a1 + a2 + a3;  // defeat DCE; scratch area in ws
    return;
  }

  // ---------------- worker blocks (identical to round 3) -------------------
  const int wgid = (int)blockIdx.x;        // 0..31
  const int b = wgid & 3;                  // batch group: rows 16b..16b+15
  const int c = wgid >> 2;                 // col group: o-cols 32c..32c+31
  const int wv = tid >> 6;                 // wave 0..3
  const int ln = tid & 63;
  const int n = ln & 15;                   // packed col in tile / A-row
  const int kq = ln >> 4;                  // quad 0..3
  const int ocol = c * 32 + wv * 8 + (n & 7);      // owned output column
  const int wrow = (n < 8) ? ocol : (256 + ocol);  // packed W row (z0|z1)
  const int arow = 16 * b + n;                     // A-fragment batch row

  __shared__ __align__(16) _Float16 mean_h[2][256];  // per-phase-parity mean

  // ---- preload W fragments (state part + x part) into registers ----
  f16x8 w0s[8], w0x[8], w1s[8], w1x[8];
  float w0pa, w0pb, w1pa, w1pb;
  {
    const float* r0 = W0 + (size_t)wrow * 514;
    const float* r1 = W1 + (size_t)wrow * 514;
#pragma unroll
    for (int kk = 0; kk < 8; ++kk) {
      const int k0 = kk * 32 + kq * 8;
      f16x8 a, bx, a1, bx1;
#pragma unroll
      for (int j = 0; j < 8; ++j) {
        a[j]   = (_Float16)r0[k0 + j];
        bx[j]  = (_Float16)r0[256 + k0 + j];
        a1[j]  = (_Float16)r1[k0 + j];
        bx1[j] = (_Float16)r1[256 + k0 + j];
      }
      w0s[kk] = a; w0x[kk] = bx; w1s[kk] = a1; w1x[kk] = bx1;
    }
    w0pa = r0[512]; w0pb = r0[513];
    w1pa = r1[512]; w1pb = r1[513];
  }

  // ---- raw recurrence state (fp32, register-resident) ----
  float raw0[4], raw1[4];
#pragma unroll
  for (int r = 0; r < 4; ++r) { raw0[r] = hs[ocol]; raw1[r] = hs[256 + ocol]; }

  // ---- init publish: uncentered h0 (f16 pairs) + tagged partials (tag 1) --
  if ((n & 1) == 0 && n < 8) {
    union { _Float16 h; unsigned short u; } e0, e1;
    e0.h = (_Float16)hs[ocol]; e1.h = (_Float16)hs[ocol + 1];
    const unsigned dw = (unsigned)e0.u | ((unsigned)e1.u << 16);
#pragma unroll
    for (int r = 0; r < 4; ++r)
      __hip_atomic_store(state0 + (size_t)(16 * b + kq * 4 + r) * 128 +
                             (ocol >> 1),
                         dw, __ATOMIC_RELAXED, __HIP_MEMORY_SCOPE_AGENT);
  }
  asm volatile("s_waitcnt vmcnt(0)" ::: "memory");
  if (kq == 0 && n < 8) {
    const float s = 16.f * hs[ocol];
    __hip_atomic_store(partH0 + (size_t)ocol * 4 + b,
                       (1ull << 32) | (unsigned long long)__float_as_uint(s),
                       __ATOMIC_RELAXED, __HIP_MEMORY_SCOPE_AGENT);
  }

// spin on this thread's column partials (4 b-groups, 32B); then mean -> LDS
#define POLLMEAN(PIN, TAG, PAR)                                                \
  {                                                                            \
    const unsigned long long* pp = (PIN) + 4 * tid;                            \
    unsigned long long q0, q1, q2, q3;                                         \
    const unsigned tg = (unsigned)(TAG);                                       \
    for (;;) {                                                                 \
      q0 = __hip_atomic_load(pp + 0, __ATOMIC_RELAXED,                         \
                             __HIP_MEMORY_SCOPE_AGENT);                        \
      q1 = __hip_atomic_load(pp + 1, __ATOMIC_RELAXED,                         \
                             __HIP_MEMORY_SCOPE_AGENT);                        \
      q2 = __hip_atomic_load(pp + 2, __ATOMIC_RELAXED,                         \
                             __HIP_MEMORY_SCOPE_AGENT);                        \
      q3 = __hip_atomic_load(pp + 3, __ATOMIC_RELAXED,                         \
                             __HIP_MEMORY_SCOPE_AGENT);                        \
      if ((unsigned)(q0 >> 32) >= tg && (unsigned)(q1 >> 32) >= tg &&          \
          (unsigned)(q2 >> 32) >= tg && (unsigned)(q3 >> 32) >= tg)            \
        break;                                                                 \
    }                                                                          \
    const float m = (__uint_as_float((unsigned)q0) +                           \
                     __uint_as_float((unsigned)q1) +                           \
                     __uint_as_float((unsigned)q2) +                           \
                     __uint_as_float((unsigned)q3)) * 0.015625f;               \
    mean_h[PAR][tid] = (_Float16)m;                                            \
  }                                                                            \
  __syncthreads();

// centered-state K-loop + gate + state/partial publish
#define TAIL(WS, SIN, SOUT, POUT, RAW, TAGOUT, PAR)                            \
  {                                                                            \
    const unsigned long long* sp =                                             \
        (const unsigned long long*)(SIN) + (size_t)arow * 64 + kq * 2;         \
    const _Float16* mh = &mean_h[PAR][kq * 8];                                 \
    _Pragma("unroll")                                                          \
    for (int kk = 0; kk < 8; ++kk) {                                           \
      union { unsigned long long q[2]; f16x8 v; } sv;                          \
      sv.q[0] = __hip_atomic_load(sp + kk * 8 + 0, __ATOMIC_RELAXED,           \
                                  __HIP_MEMORY_SCOPE_AGENT);                   \
      sv.q[1] = __hip_atomic_load(sp + kk * 8 + 1, __ATOMIC_RELAXED,           \
                                  __HIP_MEMORY_SCOPE_AGENT);                   \
      const f16x8 mv = *(const f16x8*)(mh + kk * 32);                          \
      const f16x8 av = sv.v - mv;                                              \
      acc = __builtin_amdgcn_mfma_f32_16x16x32_f16(av, WS[kk], acc, 0, 0, 0);  \
    }                                                                          \
    float nv[4], ssum = 0.f;                                                   \
    _Pragma("unroll")                                                          \
    for (int r = 0; r < 4; ++r) {                                              \
      const float z = acc[r];                                                  \
      const float p = __shfl_xor(z, 8);                                        \
      const float z0 = (n < 8) ? z : p;                                        \
      const float z1 = (n < 8) ? p : z;                                        \
      const float cv = fminf(fmaxf(z0, 0.f), 6.f) * tanhf(z1);                 \
      const float o = ((RAW)[r] + cv) * 0.5f;                                  \
      (RAW)[r] = o; nv[r] = o; ssum += o;                                      \
    }                                                                          \
    ssum += __shfl_xor(ssum, 16);                                              \
    ssum += __shfl_xor(ssum, 32);                                              \
    _Pragma("unroll")                                                          \
    for (int r = 0; r < 4; ++r) {                                              \
      union { _Float16 h; unsigned short u; } hb;                              \
      hb.h = (_Float16)nv[r];                                                  \
      const unsigned pr = (unsigned)__shfl_xor((int)hb.u, 1) & 0xFFFFu;        \
      if ((n & 1) == 0 && n < 8) {                                             \
        const unsigned dw = (unsigned)hb.u | (pr << 16);                       \
        __hip_atomic_store((SOUT) + (size_t)(16 * b + kq * 4 + r) * 128 +      \
                               (ocol >> 1),                                    \
                           dw, __ATOMIC_RELAXED, __HIP_MEMORY_SCOPE_AGENT);    \
      }                                                                        \
    }                                                                          \
    asm volatile("s_waitcnt vmcnt(0)" ::: "memory");                           \
    if (kq == 0 && n < 8)                                                      \
      __hip_atomic_store(                                                      \
          (POUT) + (size_t)ocol * 4 + b,                                       \
          ((unsigned long long)(unsigned)(TAGOUT) << 32) |                     \
              (unsigned long long)__float_as_uint(ssum),                       \
          __ATOMIC_RELAXED, __HIP_MEMORY_SCOPE_AGENT);                         \
  }

  f16x8 xa[8];
  for (int t = 0; t < T_TOT; ++t) {
    const float pe0 = (float)(t + 1);
    const float pe1 = (pe0 - 1028.5f) * (1.0f / 1028.5f);
    const int have_x = (t < S_SEQ);

    // issue x loads now; they complete while we spin in phase A's poll
    f32x4 xf[16];
    if (have_x) {
      const float* xp = xg + ((size_t)arow * S_SEQ + t) * 256 + kq * 8;
#pragma unroll
      for (int kk = 0; kk < 8; ++kk) {
        xf[2 * kk]     = *(const f32x4*)(xp + kk * 32);
        xf[2 * kk + 1] = *(const f32x4*)(xp + kk * 32 + 4);
      }
    }

    // ---------------- phase A: o1 = (h1 + calc(h0c, s, W0)) * 0.5 ----------
    {
      f32x4 acc;
      const float pt = pe0 * w0pa + pe1 * w0pb;
      acc[0] = pt; acc[1] = pt; acc[2] = pt; acc[3] = pt;
      POLLMEAN(partH0, 2 * t + 1, 0);
      if (have_x) {
#pragma unroll
        for (int kk = 0; kk < 8; ++kk) {
          f16x8 af;
#pragma unroll
          for (int j = 0; j < 4; ++j) {
            af[j]     = (_Float16)xf[2 * kk][j];
            af[4 + j] = (_Float16)xf[2 * kk + 1][j];
          }
          xa[kk] = af;
          acc = __builtin_amdgcn_mfma_f32_16x16x32_f16(af, w0x[kk], acc,
                                                       0, 0, 0);
        }
      }
      TAIL(w0s, state0, state1, partH1, raw1, 2 * t + 2, 0);
    }

    // ---------------- phase B: o0 = (h0 + calc(o1c, s, W1)) * 0.5 ----------
    {
      f32x4 acc;
      const float pt = pe0 * w1pa + pe1 * w1pb;
      acc[0] = pt; acc[1] = pt; acc[2] = pt; acc[3] = pt;
      if (have_x) {
#pragma unroll
        for (int kk = 0; kk < 8; ++kk)
          acc = __builtin_amdgcn_mfma_f32_16x16x32_f16(xa[kk], w1x[kk], acc,
                                                       0, 0, 0);
      }
      POLLMEAN(partH1, 2 * t + 2, 1);
      TAIL(w1s, state1, state0, partH0, raw0, 2 * t + 3, 1);
    }
  }

  // release the ballast blocks
  if (wgid == 0 && tid == 0)
    __hip_atomic_store(done, 1u, __ATOMIC_RELAXED, __HIP_MEMORY_SCOPE_AGENT);

  // ---- final h = [o0 | o1] fp32 ----
  if (n < 8) {
#pragma unroll
    for (int r = 0; r < 4; ++r) {
      const int row = 16 * b + kq * 4 + r;
      out[(size_t)row * 512 + ocol] = raw0[r];
      out[(size_t)row * 512 + 256 + ocol] = raw1[r];
    }
  }

#undef TAIL
#undef POLLMEAN
}

extern "C" void kernel_launch(void* const* d_in, const int* in_sizes, int n_in,
                              void* d_out, int out_size, void* d_ws, size_t ws_size,
                              hipStream_t stream) {
  (void)in_sizes; (void)n_in; (void)out_size; (void)ws_size;
  const float* x  = (const float*)d_in[0];
  const float* hs = (const float*)d_in[1];
  const float* W0 = (const float*)d_in[2];
  const float* W1 = (const float*)d_in[3];
  float* out = (float*)d_out;

  char* ws = (char*)d_ws;
  unsigned long long* partH0 = (unsigned long long*)ws;            // 8 KB
  unsigned long long* partH1 = (unsigned long long*)(ws + 8192);   // 8 KB
  unsigned* done   = (unsigned*)(ws + 16384);                      // 4 B
  float*    scr    = (float*)(ws + 16388);                         // ~1 KB
  unsigned* state0 = (unsigned*)(ws + 20480);                      // 32 KB
  unsigned* state1 = (unsigned*)(ws + 53248);                      // 32 KB

  // zero tagged partials + done flag (0xAA poison would read as valid tag /
  // as done!=0)
  hipMemsetAsync(d_ws, 0, 20480, stream);
  rnn_kernel<<<dim3(256), dim3(256), 0, stream>>>(x, hs, W0, W1, out,
                                                  partH0, partH1, done, scr,
                                                  state0, state1);
}